// Round 5
// baseline (258.456 us; speedup 1.0000x reference)
//
#include <hip/hip_runtime.h>

#define SQC 0.70710678118654752f

typedef __attribute__((ext_vector_type(8))) short bf16x8;
typedef __attribute__((ext_vector_type(4))) float f32x4;

__device__ __forceinline__ unsigned short bf16_rne(float x) {
  unsigned int u = __float_as_uint(x);
  u += 0x7FFFu + ((u >> 16) & 1u);
  return (unsigned short)(u >> 16);
}

// ---- K0: fused prep: WhT transpose-cast + lcw/lcb reorder ------------------
//   WhT[n][d] = bf16(Wh[d][n]),  n = D*16+kk          (blocks 0..127)
//   re[(l*512+dk)*576 + (j*8+sg)*24 + t]               (blocks 128..4735)
__global__ __launch_bounds__(256) void k_prep_all(const float* __restrict__ Wh,
                                                  unsigned short* __restrict__ WhT,
                                                  const float* __restrict__ lcw,
                                                  const float* __restrict__ lcb,
                                                  float* __restrict__ re) {
  int bid = blockIdx.x;
  if (bid < 128) {
    int i = bid * 256 + threadIdx.x;  // 0..32767
    int n = i >> 5, dd = i & 31;
    WhT[i] = bf16_rne(Wh[dd * 1024 + n]);
    return;
  }
  int g = (bid - 128) * 256 + threadIdx.x;  // 0..1179647
  int l = g / 294912;
  int r1 = g - l * 294912;
  int dk = r1 / 576;
  int i = r1 - dk * 576;
  int j = i / 192;
  int r = i - j * 192;
  int sg = r / 24;
  int t = r - sg * 24;
  float val = 0.f;
  if (t < 20) {
    int oi = t / 5, f = t - oi * 5;
    val = lcw[((size_t)(l * 3 + j) * 512 + dk) * 160 + (oi * 8 + sg) * 5 + f];
  } else if (t < 22) {
    val = lcb[((size_t)(l * 3 + j) * 512 + dk) * 16 + (t - 20) * 8 + sg];
  }
  re[g] = val;
}

// ---------------- K1a: zb = bf16(relu(seq @ Wg)), D-quarter per block -------
__global__ __launch_bounds__(256) void k_z(const float* __restrict__ seq,
                                           const float* __restrict__ Wg,
                                           unsigned short* __restrict__ zout) {
  int t = (blockIdx.x >> 2) * 256 + threadIdx.x;  // flat (b,l)
  int dq = blockIdx.x & 3;                        // output d-quarter (8 wide)
  const float4* srow = (const float4*)(seq + (size_t)t * 64);
  float acc[8];
#pragma unroll
  for (int i = 0; i < 8; ++i) acc[i] = 0.f;
#pragma unroll 4
  for (int D4 = 0; D4 < 16; ++D4) {
    float4 s4 = srow[D4];
    const float* sp = (const float*)&s4;
#pragma unroll
    for (int q = 0; q < 4; ++q) {
      float s = sp[q];
      int D = D4 * 4 + q;
      const float* wr = Wg + D * 32 + dq * 8;
#pragma unroll
      for (int d = 0; d < 8; ++d) acc[d] = fmaf(s, wr[d], acc[d]);
    }
  }
  uint4 o;
  unsigned int* op = (unsigned int*)&o;
#pragma unroll
  for (int i = 0; i < 4; ++i) {
    unsigned int lo = bf16_rne(fmaxf(acc[2 * i], 0.f));
    unsigned int hi = bf16_rne(fmaxf(acc[2 * i + 1], 0.f));
    op[i] = lo | (hi << 16);
  }
  *(uint4*)(zout + (size_t)t * 32 + dq * 8) = o;
}

// ------- K1b: v via MFMA: h=relu(z@Wh) fused with der contraction -----------
__global__ __launch_bounds__(256) void k_v(const unsigned short* __restrict__ zb_g,
                                           const float* __restrict__ coeffs,
                                           const unsigned short* __restrict__ WhT,
                                           float* __restrict__ v) {
  __shared__ unsigned short zs[64][40];  // bf16 rows, 32 data + 8 pad
  __shared__ float ders[64][68];
  __shared__ float vout[16][68];
  const int tid = threadIdx.x;
  const int b = blockIdx.x >> 5;
  const int lblk = (blockIdx.x & 31) * 64;
  const unsigned int* zrow_g =
      (const unsigned int*)(zb_g + ((size_t)b * 2048 + lblk) * 32);
  for (int i = tid; i < 1024; i += 256) {
    int r = i >> 4, c2 = i & 15;
    *(unsigned int*)&zs[r][c2 * 2] = zrow_g[i];
  }
  for (int i = tid; i < 4096; i += 256) {
    int r = i >> 6, D = i & 63;
    int ii = min(lblk + r, 2046);
    const float* c0 = coeffs + ((size_t)b * 2048 + ii) * 64 + D;
    ders[r][D] = c0[64] - c0[0];
  }
  __syncthreads();
  const int lane = tid & 63;
  const int wv = tid >> 6;
  const int col = lane & 15, quad = lane >> 4;
  bf16x8 afrag = *(bf16x8*)&zs[wv * 16 + col][quad * 8];
  f32x4 vacc = {0.f, 0.f, 0.f, 0.f};
  const unsigned short* bptr = WhT + col * 32 + quad * 8;
  const int lrow0 = wv * 16 + quad * 4;
#pragma unroll 4
  for (int t = 0; t < 64; ++t) {
    bf16x8 bfrag = *(const bf16x8*)(bptr + t * 512);
    f32x4 c = {0.f, 0.f, 0.f, 0.f};
    c = __builtin_amdgcn_mfma_f32_16x16x32_bf16(afrag, bfrag, c, 0, 0, 0);
#pragma unroll
    for (int r = 0; r < 4; ++r)
      vacc[r] = fmaf(fmaxf(c[r], 0.f), ders[lrow0 + r][t], vacc[r]);
  }
#pragma unroll
  for (int r = 0; r < 4; ++r) vout[col][lrow0 + r] = vacc[r];
  __syncthreads();
  for (int i = tid; i < 1024; i += 256) {
    int kk = i >> 6, ll = i & 63;
    v[((size_t)b * 16 + kk) * 2048 + lblk + ll] = vout[kk][ll];
  }
}

// ---- K2: 4-level Haar dec, fully register-local: one wave per (b,k) --------
__global__ __launch_bounds__(64) void k_haar(const float* __restrict__ v,
                                             float* __restrict__ wdet,
                                             float* __restrict__ wapp,
                                             float* __restrict__ a0T) {
  const int bk = blockIdx.x;  // b*16 + k
  const int L = threadIdx.x;  // lane 0..63
  const float* src = v + (size_t)bk * 2048 + L * 32;
  float x[32];
#pragma unroll
  for (int j = 0; j < 8; ++j) *(float4*)&x[4 * j] = ((const float4*)src)[j];
  const size_t base = (size_t)bk * 1920;
  // level 0: 32 -> 16
  float ca0[16], cd0[16];
#pragma unroll
  for (int i = 0; i < 16; ++i) {
    ca0[i] = (x[2 * i] + x[2 * i + 1]) * SQC;
    cd0[i] = (x[2 * i] - x[2 * i + 1]) * SQC;
  }
  {
    float* wd = wdet + base + L * 16;
    float* wa = wapp + base + L * 16;
#pragma unroll
    for (int j = 0; j < 4; ++j) {
      *(float4*)(wd + 4 * j) = *(float4*)&cd0[4 * j];
      *(float4*)(wa + 4 * j) = *(float4*)&ca0[4 * j];
    }
  }
  // level 1: 16 -> 8
  float ca1[8], cd1[8];
#pragma unroll
  for (int i = 0; i < 8; ++i) {
    ca1[i] = (ca0[2 * i] + ca0[2 * i + 1]) * SQC;
    cd1[i] = (ca0[2 * i] - ca0[2 * i + 1]) * SQC;
  }
  {
    float* wd = wdet + base + 1024 + L * 8;
    float* wa = wapp + base + 1024 + L * 8;
#pragma unroll
    for (int j = 0; j < 2; ++j) {
      *(float4*)(wd + 4 * j) = *(float4*)&cd1[4 * j];
      *(float4*)(wa + 4 * j) = *(float4*)&ca1[4 * j];
    }
  }
  // level 2: 8 -> 4
  float ca2[4], cd2[4];
#pragma unroll
  for (int i = 0; i < 4; ++i) {
    ca2[i] = (ca1[2 * i] + ca1[2 * i + 1]) * SQC;
    cd2[i] = (ca1[2 * i] - ca1[2 * i + 1]) * SQC;
  }
  *(float4*)(wdet + base + 1536 + L * 4) = *(float4*)&cd2[0];
  *(float4*)(wapp + base + 1536 + L * 4) = *(float4*)&ca2[0];
  // level 3: 4 -> 2
  float ca3[2], cd3[2];
#pragma unroll
  for (int i = 0; i < 2; ++i) {
    ca3[i] = (ca2[2 * i] + ca2[2 * i + 1]) * SQC;
    cd3[i] = (ca2[2 * i] - ca2[2 * i + 1]) * SQC;
  }
  *(float2*)(wdet + base + 1792 + L * 2) = *(float2*)&cd3[0];
  *(float2*)(wapp + base + 1792 + L * 2) = *(float2*)&ca3[0];
  // approx3 transposed: a0T[k][q][b], q = 2L, 2L+1
  const int k = bk & 15, bb = bk >> 4;
  a0T[((size_t)k * 128 + 2 * L) * 16 + bb] = ca3[0];
  a0T[((size_t)k * 128 + 2 * L + 1) * 16 + bb] = ca3[1];
}

// ---- K3: fused 3-layer dense chain, one block per dk, LDS double-buffer ----
__global__ __launch_bounds__(256) void k_dense3(const float* __restrict__ dW,
                                                const float* __restrict__ a0T,
                                                float* __restrict__ curd) {
  __shared__ float bufA[128 * 20];
  __shared__ float bufB[128 * 20];
  const int tid = threadIdx.x;
  const int dk = blockIdx.x;
  const int d = dk >> 4, k = dk & 15;
  {
    const float* src = a0T + (size_t)k * 2048;
    for (int i = tid; i < 2048; i += 256) {
      int q = i >> 4, b = i & 15;
      bufA[q * 20 + b] = src[i];
    }
  }
  const int t = tid & 127;
  const int bh = (tid >> 7) << 3;  // 0 or 8
  float acc[8];
  float* bin = bufA;
  float* bout = bufB;
#pragma unroll 1
  for (int j = 0; j < 3; ++j) {
    __syncthreads();
    const float* Wt = dW + ((size_t)j * 512 + dk) * 16384 + (size_t)t * 128;
#pragma unroll
    for (int i = 0; i < 8; ++i) acc[i] = 0.f;
#pragma unroll 4
    for (int q4 = 0; q4 < 32; ++q4) {
      float4 wv4 = ((const float4*)Wt)[q4];
      const float* wp = (const float*)&wv4;
#pragma unroll
      for (int qq = 0; qq < 4; ++qq) {
        int q = q4 * 4 + qq;
        float w = wp[qq];
        const float* ar = bin + q * 20 + bh;
        float4 a0 = *(const float4*)(ar);
        float4 a1 = *(const float4*)(ar + 4);
        acc[0] = fmaf(w, a0.x, acc[0]); acc[1] = fmaf(w, a0.y, acc[1]);
        acc[2] = fmaf(w, a0.z, acc[2]); acc[3] = fmaf(w, a0.w, acc[3]);
        acc[4] = fmaf(w, a1.x, acc[4]); acc[5] = fmaf(w, a1.y, acc[5]);
        acc[6] = fmaf(w, a1.z, acc[6]); acc[7] = fmaf(w, a1.w, acc[7]);
      }
    }
    if (j < 2) {
      float* orow = bout + t * 20 + bh;
      *(float4*)orow = make_float4(acc[0], acc[1], acc[2], acc[3]);
      *(float4*)(orow + 4) = make_float4(acc[4], acc[5], acc[6], acc[7]);
      float* tmp = bin; bin = bout; bout = tmp;
    }
  }
#pragma unroll
  for (int i = 0; i < 8; ++i) {
    int b = bh + i;
    curd[(((size_t)b * 32 + d) * 16 + k) * 128 + t] = acc[i];
  }
}

// ======================= fused wave-per-chain LC kernel =====================
__device__ __forceinline__ void loadw24(float (&wl)[24], const float* p) {
#pragma unroll
  for (int i = 0; i < 6; ++i) *(float4*)&wl[4 * i] = *(const float4*)(p + 4 * i);
}

// one LC layer, IN-PLACE rolling window: x gets overwritten with relu(conv(x)).
// halo via shfl; 2-deep history keeps peak register pressure at ~2P+temps.
template <int P>
__device__ __forceinline__ void conv_inplace(int lane, const float (&wl)[24],
                                             float (&x0)[P], float (&x1)[P]) {
  float l00 = __shfl_up(x0[P - 2], 1), l01 = __shfl_up(x0[P - 1], 1);
  float l10 = __shfl_up(x1[P - 2], 1), l11 = __shfl_up(x1[P - 1], 1);
  float r00 = __shfl_down(x0[0], 1), r01 = __shfl_down(x0[1], 1);
  float r10 = __shfl_down(x1[0], 1), r11 = __shfl_down(x1[1], 1);
  if (lane == 0) { l00 = 0.f; l01 = 0.f; l10 = 0.f; l11 = 0.f; }
  if (lane == 63) { r00 = 0.f; r01 = 0.f; r10 = 0.f; r11 = 0.f; }
  float a0 = l00, b0 = l01, a1 = l10, b1 = l11;
#pragma unroll
  for (int i = 0; i < P; ++i) {
    float c0 = x0[i], c1 = x1[i];
    float d0 = (i + 1 < P) ? x0[i + 1] : r00;
    float d1 = (i + 1 < P) ? x1[i + 1] : r10;
    float e0 = (i + 2 < P) ? x0[i + 2] : ((i + 2 == P) ? r00 : r01);
    float e1 = (i + 2 < P) ? x1[i + 2] : ((i + 2 == P) ? r10 : r11);
    float o0 = wl[20], o1 = wl[21];
    o0 = fmaf(wl[0], a0, o0); o0 = fmaf(wl[1], b0, o0); o0 = fmaf(wl[2], c0, o0);
    o0 = fmaf(wl[3], d0, o0); o0 = fmaf(wl[4], e0, o0);
    o0 = fmaf(wl[5], a1, o0); o0 = fmaf(wl[6], b1, o0); o0 = fmaf(wl[7], c1, o0);
    o0 = fmaf(wl[8], d1, o0); o0 = fmaf(wl[9], e1, o0);
    o1 = fmaf(wl[10], a0, o1); o1 = fmaf(wl[11], b0, o1); o1 = fmaf(wl[12], c0, o1);
    o1 = fmaf(wl[13], d0, o1); o1 = fmaf(wl[14], e0, o1);
    o1 = fmaf(wl[15], a1, o1); o1 = fmaf(wl[16], b1, o1); o1 = fmaf(wl[17], c1, o1);
    o1 = fmaf(wl[18], d1, o1); o1 = fmaf(wl[19], e1, o1);
    a0 = b0; b0 = c0; a1 = b1; b1 = c1;
    x0[i] = fmaxf(o0, 0.f);
    x1[i] = fmaxf(o1, 0.f);
  }
}

// 3 conv layers, in-place
template <int P>
__device__ __forceinline__ void conv3(int lane, const float* wb, int seg,
                                      float (&x0)[P], float (&x1)[P]) {
  float wl[24];
  loadw24(wl, wb + (0 * 8 + seg) * 24);
  conv_inplace<P>(lane, wl, x0, x1);
  loadw24(wl, wb + (1 * 8 + seg) * 24);
  conv_inplace<P>(lane, wl, x0, x1);
  loadw24(wl, wb + (2 * 8 + seg) * 24);
  conv_inplace<P>(lane, wl, x0, x1);
}

template <int P>
__device__ __forceinline__ void haar_rec_reg(const float (&x0)[P], const float (&x1)[P],
                                             const float (&cur)[P], float (&nxt)[2 * P]) {
#pragma unroll
  for (int i = 0; i < P; ++i) {
    float X1 = x1[i] + cur[i], X0 = x0[i];
    nxt[2 * i] = (X1 + X0) * SQC;
    nxt[2 * i + 1] = (X1 - X0) * SQC;
  }
}

// float4 chi loads for P>=4 (offsets are P-aligned), float2 at P=2
template <int P>
__device__ __forceinline__ void load_chi(const float* __restrict__ wdet,
                                         const float* __restrict__ wapp,
                                         size_t off, float (&x0)[P], float (&x1)[P]) {
  if constexpr (P >= 4) {
#pragma unroll
    for (int i = 0; i < P; i += 4) {
      *(float4*)&x0[i] = *(const float4*)(wdet + off + i);
      *(float4*)&x1[i] = *(const float4*)(wapp + off + i);
    }
  } else {
#pragma unroll
    for (int i = 0; i < P; i += 2) {
      *(float2*)&x0[i] = *(const float2*)(wdet + off + i);
      *(float2*)&x1[i] = *(const float2*)(wapp + off + i);
    }
  }
}

// K4: block=(b,d,kg); wave wv = full chain k=kg*4+wv through levels 3..0.
// Software-pipelined: weight staging split into issue (global->reg) and
// commit (reg->LDS, double-buffered slots); chi loads for level l-1 issued
// before conv of level l.  Load latency hides under the previous conv.
__global__ __launch_bounds__(256, 2) void k_lc(const float* __restrict__ wdet,
                                               const float* __restrict__ wapp,
                                               const float* __restrict__ curd,
                                               const float* __restrict__ lcw_re,
                                               float* __restrict__ osum01,
                                               float* __restrict__ osum23) {
  __shared__ float wbuf[4][2][584];  // [wave][slot] weight slabs (18.7 KB)
  __shared__ float accb[2][2112];    // two reduction slabs, +33 padded (16.9 KB)
  const int tid = threadIdx.x;
  const int lane = tid & 63;
  const int wv = tid >> 6;
  const int kg = blockIdx.x & 3;
  const int d = (blockIdx.x >> 2) & 31;
  const int b = blockIdx.x >> 7;
  const int k = kg * 4 + wv;
  const int bk = b * 16 + k;
  const int dk = d * 16 + k;
  const int seg = lane >> 3;  // same seg mapping at every level
  const size_t base = (size_t)bk * 1920;

  struct StReg { float4 a, b, c; };
  auto stage_issue = [&](int l) {
    const float4* src = (const float4*)(lcw_re + ((size_t)(l * 512) + dk) * 576);
    StReg r;
    r.a = src[lane];
    r.b = src[lane + 64];
    if (lane < 16) r.c = src[lane + 128];
    return r;
  };
  auto stage_commit = [&](const StReg& r, int slot) {
    float4* dst = (float4*)wbuf[wv][slot];
    dst[lane] = r.a;
    dst[lane + 64] = r.b;
    if (lane < 16) dst[lane + 128] = r.c;
  };

  // -------- prologue: issue L3+L2 weights, L3+L2 chi, curd ----------
  StReg r3 = stage_issue(3);
  StReg r2 = stage_issue(2);
  float c3x0[2], c3x1[2], c3[2];
  load_chi<2>(wdet, wapp, base + 1792 + lane * 2, c3x0, c3x1);
  *(float2*)&c3[0] =
      *(const float2*)(curd + (((size_t)b * 32 + d) * 16 + k) * 128 + lane * 2);
  float c2x0[4], c2x1[4];
  load_chi<4>(wdet, wapp, base + 1536 + lane * 4, c2x0, c2x1);
  stage_commit(r3, 0);

  // ---- level 3 (P=2) ----
  float cur4[4];
  conv3<2>(lane, wbuf[wv][0], seg, c3x0, c3x1);
  haar_rec_reg<2>(c3x0, c3x1, c3, cur4);

  // issue L1 ahead
  StReg r1 = stage_issue(1);
  float c1x0[8], c1x1[8];
  load_chi<8>(wdet, wapp, base + 1024 + lane * 8, c1x0, c1x1);
  stage_commit(r2, 1);

  // ---- level 2 (P=4) ----
  float cur8[8];
  conv3<4>(lane, wbuf[wv][1], seg, c2x0, c2x1);
  haar_rec_reg<4>(c2x0, c2x1, cur4, cur8);

  // issue L0 ahead
  StReg r0 = stage_issue(0);
  float c0x0[16], c0x1[16];
  load_chi<16>(wdet, wapp, base + lane * 16, c0x0, c0x1);
  stage_commit(r1, 0);

  // ---- level 1 (P=8) ----
  float cur16[16];
  conv3<8>(lane, wbuf[wv][0], seg, c1x0, c1x1);
  haar_rec_reg<8>(c1x0, c1x1, cur8, cur16);
  stage_commit(r0, 1);

  // ---- level 0 (P=16), final rec fused into the two-phase LDS reduction ----
  {
    conv3<16>(lane, wbuf[wv][1], seg, c0x0, c0x1);
    float* arow = &accb[wv & 1][lane * 33];
    if (wv >= 2) {  // waves 2,3 initialize the two slabs
#pragma unroll
      for (int i = 0; i < 16; ++i) {
        float X1 = c0x1[i] + cur16[i], X0 = c0x0[i];
        arow[2 * i] = (X1 + X0) * SQC;
        arow[2 * i + 1] = (X1 - X0) * SQC;
      }
    }
    __syncthreads();
    if (wv < 2) {  // waves 0,1 accumulate into them
#pragma unroll
      for (int i = 0; i < 16; ++i) {
        float X1 = c0x1[i] + cur16[i], X0 = c0x0[i];
        arow[2 * i] += (X1 + X0) * SQC;
        arow[2 * i + 1] += (X1 - X0) * SQC;
      }
    }
  }
  __syncthreads();
  // block reduction over the 2 slabs -> one osum partial slab row
  float* obase = (kg < 2) ? osum01 : osum23;
  float* orow = obase + ((size_t)(kg & 1) * 512 + (size_t)b * 32 + d) * 2048;
#pragma unroll
  for (int r = 0; r < 8; ++r) {
    int p = r * 256 + tid;
    int L = p >> 5, J = p & 31;
    int a = L * 33 + J;
    orow[p] = accb[0][a] + accb[1][a];
  }
}

// ------- K5: U[b,l,Dq] = sum_d (sum of 4 osum slabs) * Wrev[d,Dq] -----------
__global__ __launch_bounds__(256) void k_final(const float* __restrict__ osum01,
                                               const float* __restrict__ osum23,
                                               const float* __restrict__ Wrev,
                                               float* __restrict__ U) {
  int t = (blockIdx.x >> 2) * 256 + threadIdx.x;
  int Dq = blockIdx.x & 3;
  int b = t >> 11, l = t & 2047;
  float acc[16];
#pragma unroll
  for (int i = 0; i < 16; ++i) acc[i] = 0.f;
  for (int dd = 0; dd < 32; ++dd) {
    size_t off = ((size_t)b * 32 + dd) * 2048 + l;
    float x = osum01[off] + osum01[off + 1048576] +
              osum23[off] + osum23[off + 1048576];
    const float* wr = Wrev + dd * 64 + Dq * 16;
#pragma unroll
    for (int j = 0; j < 16; ++j) acc[j] = fmaf(x, wr[j], acc[j]);
  }
  float* o = U + (size_t)t * 64 + Dq * 16;
#pragma unroll
  for (int i = 0; i < 4; ++i)
    *(float4*)(o + 4 * i) =
        make_float4(acc[4 * i], acc[4 * i + 1], acc[4 * i + 2], acc[4 * i + 3]);
}

extern "C" void kernel_launch(void* const* d_in, const int* in_sizes, int n_in,
                              void* d_out, int out_size, void* d_ws, size_t ws_size,
                              hipStream_t stream) {
  const float* seq    = (const float*)d_in[0];
  const float* coeffs = (const float*)d_in[1];
  // d_in[2]=time, d_in[3]=time_step: arange(2048), dt==1 -> folded.
  const float* Wg   = (const float*)d_in[4];
  const float* Wh   = (const float*)d_in[5];
  const float* dW   = (const float*)d_in[6];
  const float* lcw  = (const float*)d_in[7];
  const float* lcb  = (const float*)d_in[8];
  const float* Wrev = (const float*)d_in[9];
  float* out = (float*)d_out;

  // workspace layout (float units), aliased by lifetime:
  float* w      = (float*)d_ws;
  unsigned short* zb16 = (unsigned short*)(w + 0);  // 1Mi bf16 [k_z -> k_v]
  float* v      = w + 1048576;    //   524,288  [k_v -> k_haar]
  float* a0T    = w + 1572864;    //    32,768  [k_haar -> dense]
  unsigned short* WhT = (unsigned short*)(w + 1572864 + 16384);  // [prep -> k_v]
  float* lcw_re = w + 1605632;    // 1,179,648  [prep -> k_lc]
  float* curd   = w + 3702784;    // 1,048,576  [dense3 -> k_lc]
  float* osum01 = w + 4751360;    // 2,097,152  [k_lc -> final]
  float* wdet   = w + 6848512;    //   491,520  [k_haar -> k_lc]
  float* wapp   = w + 7340032;    //   491,520
  float* osum23 = w + 7831552;    // 2,097,152  [k_lc -> final]  (~39.7 MB)

  k_prep_all<<<4736, 256, 0, stream>>>(Wh, WhT, lcw, lcb, lcw_re);
  k_z<<<512, 256, 0, stream>>>(seq, Wg, zb16);
  k_v<<<512, 256, 0, stream>>>(zb16, coeffs, WhT, v);
  k_haar<<<256, 64, 0, stream>>>(v, wdet, wapp, a0T);
  k_dense3<<<512, 256, 0, stream>>>(dW, a0T, curd);
  k_lc<<<2048, 256, 0, stream>>>(wdet, wapp, curd, lcw_re, osum01, osum23);
  k_final<<<512, 256, 0, stream>>>(osum01, osum23, Wrev, out);
}

// Round 6
// 255.084 us; speedup vs baseline: 1.0132x; 1.0132x over previous
//
#include <hip/hip_runtime.h>

#define SQC 0.70710678118654752f

typedef __attribute__((ext_vector_type(8))) short bf16x8;
typedef __attribute__((ext_vector_type(4))) float f32x4;

__device__ __forceinline__ unsigned short bf16_rne(float x) {
  unsigned int u = __float_as_uint(x);
  u += 0x7FFFu + ((u >> 16) & 1u);
  return (unsigned short)(u >> 16);
}

// ---- K0: fused prep: WhT transpose-cast + lcw/lcb reorder ------------------
//   WhT[n][d] = bf16(Wh[d][n]),  n = D*16+kk          (blocks 0..127)
//   re[(l*512+dk)*576 + (j*8+sg)*24 + t]               (blocks 128..4735)
__global__ __launch_bounds__(256) void k_prep_all(const float* __restrict__ Wh,
                                                  unsigned short* __restrict__ WhT,
                                                  const float* __restrict__ lcw,
                                                  const float* __restrict__ lcb,
                                                  float* __restrict__ re) {
  int bid = blockIdx.x;
  if (bid < 128) {
    int i = bid * 256 + threadIdx.x;  // 0..32767
    int n = i >> 5, dd = i & 31;
    WhT[i] = bf16_rne(Wh[dd * 1024 + n]);
    return;
  }
  int g = (bid - 128) * 256 + threadIdx.x;  // 0..1179647
  int l = g / 294912;
  int r1 = g - l * 294912;
  int dk = r1 / 576;
  int i = r1 - dk * 576;
  int j = i / 192;
  int r = i - j * 192;
  int sg = r / 24;
  int t = r - sg * 24;
  float val = 0.f;
  if (t < 20) {
    int oi = t / 5, f = t - oi * 5;
    val = lcw[((size_t)(l * 3 + j) * 512 + dk) * 160 + (oi * 8 + sg) * 5 + f];
  } else if (t < 22) {
    val = lcb[((size_t)(l * 3 + j) * 512 + dk) * 16 + (t - 20) * 8 + sg];
  }
  re[g] = val;
}

// ------- K1: fused z + v.  z = bf16(relu(seq@Wg)) computed in-block into LDS,
//         then h=relu(z@Wh) via MFMA fused with the der contraction. ---------
__global__ __launch_bounds__(256) void k_zv(const float* __restrict__ seq,
                                            const float* __restrict__ Wg,
                                            const float* __restrict__ coeffs,
                                            const unsigned short* __restrict__ WhT,
                                            float* __restrict__ v) {
  __shared__ unsigned short zs[64][40];  // bf16 rows, 32 data + 8 pad
  __shared__ float ders[64][68];
  __shared__ float vout[16][68];
  const int tid = threadIdx.x;
  const int b = blockIdx.x >> 5;
  const int lblk = (blockIdx.x & 31) * 64;
  // --- z for rows lblk..lblk+63: thread (r, dq) computes 8 outputs ---
  {
    const int r = tid >> 2;  // 0..63
    const int dq = tid & 3;  // d-quarter (8 wide)
    const float4* srow = (const float4*)(seq + ((size_t)b * 2048 + lblk + r) * 64);
    float acc[8];
#pragma unroll
    for (int i = 0; i < 8; ++i) acc[i] = 0.f;
#pragma unroll 4
    for (int D4 = 0; D4 < 16; ++D4) {
      float4 s4 = srow[D4];
      const float* sp = (const float*)&s4;
#pragma unroll
      for (int q = 0; q < 4; ++q) {
        float s = sp[q];
        int D = D4 * 4 + q;
        const float* wr = Wg + D * 32 + dq * 8;
#pragma unroll
        for (int dd2 = 0; dd2 < 8; ++dd2) acc[dd2] = fmaf(s, wr[dd2], acc[dd2]);
      }
    }
    uint4 o;
    unsigned int* op = (unsigned int*)&o;
#pragma unroll
    for (int i = 0; i < 4; ++i) {
      unsigned int lo = bf16_rne(fmaxf(acc[2 * i], 0.f));
      unsigned int hi = bf16_rne(fmaxf(acc[2 * i + 1], 0.f));
      op[i] = lo | (hi << 16);
    }
    *(uint4*)&zs[r][dq * 8] = o;  // r*80+dq*16 bytes: 16B-aligned
  }
  // --- ders ---
  for (int i = tid; i < 4096; i += 256) {
    int r = i >> 6, D = i & 63;
    int ii = min(lblk + r, 2046);
    const float* c0 = coeffs + ((size_t)b * 2048 + ii) * 64 + D;
    ders[r][D] = c0[64] - c0[0];
  }
  __syncthreads();
  const int lane = tid & 63;
  const int wv = tid >> 6;
  const int col = lane & 15, quad = lane >> 4;
  bf16x8 afrag = *(bf16x8*)&zs[wv * 16 + col][quad * 8];
  f32x4 vacc = {0.f, 0.f, 0.f, 0.f};
  const unsigned short* bptr = WhT + col * 32 + quad * 8;
  const int lrow0 = wv * 16 + quad * 4;
#pragma unroll 4
  for (int t = 0; t < 64; ++t) {
    bf16x8 bfrag = *(const bf16x8*)(bptr + t * 512);
    f32x4 c = {0.f, 0.f, 0.f, 0.f};
    c = __builtin_amdgcn_mfma_f32_16x16x32_bf16(afrag, bfrag, c, 0, 0, 0);
#pragma unroll
    for (int r = 0; r < 4; ++r)
      vacc[r] = fmaf(fmaxf(c[r], 0.f), ders[lrow0 + r][t], vacc[r]);
  }
#pragma unroll
  for (int r = 0; r < 4; ++r) vout[col][lrow0 + r] = vacc[r];
  __syncthreads();
  for (int i = tid; i < 1024; i += 256) {
    int kk = i >> 6, ll = i & 63;
    v[((size_t)b * 16 + kk) * 2048 + lblk + ll] = vout[kk][ll];
  }
}

// ---- K2: 4-level Haar dec, fully register-local: one wave per (b,k) --------
__global__ __launch_bounds__(64) void k_haar(const float* __restrict__ v,
                                             float* __restrict__ wdet,
                                             float* __restrict__ wapp,
                                             float* __restrict__ a0T) {
  const int bk = blockIdx.x;  // b*16 + k
  const int L = threadIdx.x;  // lane 0..63
  const float* src = v + (size_t)bk * 2048 + L * 32;
  float x[32];
#pragma unroll
  for (int j = 0; j < 8; ++j) *(float4*)&x[4 * j] = ((const float4*)src)[j];
  const size_t base = (size_t)bk * 1920;
  // level 0: 32 -> 16
  float ca0[16], cd0[16];
#pragma unroll
  for (int i = 0; i < 16; ++i) {
    ca0[i] = (x[2 * i] + x[2 * i + 1]) * SQC;
    cd0[i] = (x[2 * i] - x[2 * i + 1]) * SQC;
  }
  {
    float* wd = wdet + base + L * 16;
    float* wa = wapp + base + L * 16;
#pragma unroll
    for (int j = 0; j < 4; ++j) {
      *(float4*)(wd + 4 * j) = *(float4*)&cd0[4 * j];
      *(float4*)(wa + 4 * j) = *(float4*)&ca0[4 * j];
    }
  }
  // level 1: 16 -> 8
  float ca1[8], cd1[8];
#pragma unroll
  for (int i = 0; i < 8; ++i) {
    ca1[i] = (ca0[2 * i] + ca0[2 * i + 1]) * SQC;
    cd1[i] = (ca0[2 * i] - ca0[2 * i + 1]) * SQC;
  }
  {
    float* wd = wdet + base + 1024 + L * 8;
    float* wa = wapp + base + 1024 + L * 8;
#pragma unroll
    for (int j = 0; j < 2; ++j) {
      *(float4*)(wd + 4 * j) = *(float4*)&cd1[4 * j];
      *(float4*)(wa + 4 * j) = *(float4*)&ca1[4 * j];
    }
  }
  // level 2: 8 -> 4
  float ca2[4], cd2[4];
#pragma unroll
  for (int i = 0; i < 4; ++i) {
    ca2[i] = (ca1[2 * i] + ca1[2 * i + 1]) * SQC;
    cd2[i] = (ca1[2 * i] - ca1[2 * i + 1]) * SQC;
  }
  *(float4*)(wdet + base + 1536 + L * 4) = *(float4*)&cd2[0];
  *(float4*)(wapp + base + 1536 + L * 4) = *(float4*)&ca2[0];
  // level 3: 4 -> 2
  float ca3[2], cd3[2];
#pragma unroll
  for (int i = 0; i < 2; ++i) {
    ca3[i] = (ca2[2 * i] + ca2[2 * i + 1]) * SQC;
    cd3[i] = (ca2[2 * i] - ca2[2 * i + 1]) * SQC;
  }
  *(float2*)(wdet + base + 1792 + L * 2) = *(float2*)&cd3[0];
  *(float2*)(wapp + base + 1792 + L * 2) = *(float2*)&ca3[0];
  // approx3 transposed: a0T[k][q][b], q = 2L, 2L+1
  const int k = bk & 15, bb = bk >> 4;
  a0T[((size_t)k * 128 + 2 * L) * 16 + bb] = ca3[0];
  a0T[((size_t)k * 128 + 2 * L + 1) * 16 + bb] = ca3[1];
}

// ---- K3: fused 3-layer dense chain, one block per dk, LDS double-buffer ----
__global__ __launch_bounds__(256) void k_dense3(const float* __restrict__ dW,
                                                const float* __restrict__ a0T,
                                                float* __restrict__ curd) {
  __shared__ float bufA[128 * 20];
  __shared__ float bufB[128 * 20];
  const int tid = threadIdx.x;
  const int dk = blockIdx.x;
  const int d = dk >> 4, k = dk & 15;
  {
    const float* src = a0T + (size_t)k * 2048;
    for (int i = tid; i < 2048; i += 256) {
      int q = i >> 4, b = i & 15;
      bufA[q * 20 + b] = src[i];
    }
  }
  const int t = tid & 127;
  const int bh = (tid >> 7) << 3;  // 0 or 8
  float acc[8];
  float* bin = bufA;
  float* bout = bufB;
#pragma unroll 1
  for (int j = 0; j < 3; ++j) {
    __syncthreads();
    const float* Wt = dW + ((size_t)j * 512 + dk) * 16384 + (size_t)t * 128;
#pragma unroll
    for (int i = 0; i < 8; ++i) acc[i] = 0.f;
#pragma unroll 4
    for (int q4 = 0; q4 < 32; ++q4) {
      float4 wv4 = ((const float4*)Wt)[q4];
      const float* wp = (const float*)&wv4;
#pragma unroll
      for (int qq = 0; qq < 4; ++qq) {
        int q = q4 * 4 + qq;
        float w = wp[qq];
        const float* ar = bin + q * 20 + bh;
        float4 a0 = *(const float4*)(ar);
        float4 a1 = *(const float4*)(ar + 4);
        acc[0] = fmaf(w, a0.x, acc[0]); acc[1] = fmaf(w, a0.y, acc[1]);
        acc[2] = fmaf(w, a0.z, acc[2]); acc[3] = fmaf(w, a0.w, acc[3]);
        acc[4] = fmaf(w, a1.x, acc[4]); acc[5] = fmaf(w, a1.y, acc[5]);
        acc[6] = fmaf(w, a1.z, acc[6]); acc[7] = fmaf(w, a1.w, acc[7]);
      }
    }
    if (j < 2) {
      float* orow = bout + t * 20 + bh;
      *(float4*)orow = make_float4(acc[0], acc[1], acc[2], acc[3]);
      *(float4*)(orow + 4) = make_float4(acc[4], acc[5], acc[6], acc[7]);
      float* tmp = bin; bin = bout; bout = tmp;
    }
  }
#pragma unroll
  for (int i = 0; i < 8; ++i) {
    int b = bh + i;
    curd[(((size_t)b * 32 + d) * 16 + k) * 128 + t] = acc[i];
  }
}

// ======================= fused wave-per-chain LC kernel =====================
__device__ __forceinline__ void loadw24(float (&wl)[24], const float* p) {
#pragma unroll
  for (int i = 0; i < 6; ++i) *(float4*)&wl[4 * i] = *(const float4*)(p + 4 * i);
}

// one LC layer, IN-PLACE rolling window: x gets overwritten with relu(conv(x)).
// halo via shfl; 2-deep history keeps peak register pressure at ~2P+temps.
template <int P>
__device__ __forceinline__ void conv_inplace(int lane, const float (&wl)[24],
                                             float (&x0)[P], float (&x1)[P]) {
  float l00 = __shfl_up(x0[P - 2], 1), l01 = __shfl_up(x0[P - 1], 1);
  float l10 = __shfl_up(x1[P - 2], 1), l11 = __shfl_up(x1[P - 1], 1);
  float r00 = __shfl_down(x0[0], 1), r01 = __shfl_down(x0[1], 1);
  float r10 = __shfl_down(x1[0], 1), r11 = __shfl_down(x1[1], 1);
  if (lane == 0) { l00 = 0.f; l01 = 0.f; l10 = 0.f; l11 = 0.f; }
  if (lane == 63) { r00 = 0.f; r01 = 0.f; r10 = 0.f; r11 = 0.f; }
  float a0 = l00, b0 = l01, a1 = l10, b1 = l11;
#pragma unroll
  for (int i = 0; i < P; ++i) {
    float c0 = x0[i], c1 = x1[i];
    float d0 = (i + 1 < P) ? x0[i + 1] : r00;
    float d1 = (i + 1 < P) ? x1[i + 1] : r10;
    float e0 = (i + 2 < P) ? x0[i + 2] : ((i + 2 == P) ? r00 : r01);
    float e1 = (i + 2 < P) ? x1[i + 2] : ((i + 2 == P) ? r10 : r11);
    float o0 = wl[20], o1 = wl[21];
    o0 = fmaf(wl[0], a0, o0); o0 = fmaf(wl[1], b0, o0); o0 = fmaf(wl[2], c0, o0);
    o0 = fmaf(wl[3], d0, o0); o0 = fmaf(wl[4], e0, o0);
    o0 = fmaf(wl[5], a1, o0); o0 = fmaf(wl[6], b1, o0); o0 = fmaf(wl[7], c1, o0);
    o0 = fmaf(wl[8], d1, o0); o0 = fmaf(wl[9], e1, o0);
    o1 = fmaf(wl[10], a0, o1); o1 = fmaf(wl[11], b0, o1); o1 = fmaf(wl[12], c0, o1);
    o1 = fmaf(wl[13], d0, o1); o1 = fmaf(wl[14], e0, o1);
    o1 = fmaf(wl[15], a1, o1); o1 = fmaf(wl[16], b1, o1); o1 = fmaf(wl[17], c1, o1);
    o1 = fmaf(wl[18], d1, o1); o1 = fmaf(wl[19], e1, o1);
    a0 = b0; b0 = c0; a1 = b1; b1 = c1;
    x0[i] = fmaxf(o0, 0.f);
    x1[i] = fmaxf(o1, 0.f);
  }
}

// 3 conv layers, in-place
template <int P>
__device__ __forceinline__ void conv3(int lane, const float* wb, int seg,
                                      float (&x0)[P], float (&x1)[P]) {
  float wl[24];
  loadw24(wl, wb + (0 * 8 + seg) * 24);
  conv_inplace<P>(lane, wl, x0, x1);
  loadw24(wl, wb + (1 * 8 + seg) * 24);
  conv_inplace<P>(lane, wl, x0, x1);
  loadw24(wl, wb + (2 * 8 + seg) * 24);
  conv_inplace<P>(lane, wl, x0, x1);
}

template <int P>
__device__ __forceinline__ void haar_rec_reg(const float (&x0)[P], const float (&x1)[P],
                                             const float (&cur)[P], float (&nxt)[2 * P]) {
#pragma unroll
  for (int i = 0; i < P; ++i) {
    float X1 = x1[i] + cur[i], X0 = x0[i];
    nxt[2 * i] = (X1 + X0) * SQC;
    nxt[2 * i + 1] = (X1 - X0) * SQC;
  }
}

// float4 chi loads for P>=4 (offsets are P-aligned), float2 at P=2
template <int P>
__device__ __forceinline__ void load_chi(const float* __restrict__ wdet,
                                         const float* __restrict__ wapp,
                                         size_t off, float (&x0)[P], float (&x1)[P]) {
  if constexpr (P >= 4) {
#pragma unroll
    for (int i = 0; i < P; i += 4) {
      *(float4*)&x0[i] = *(const float4*)(wdet + off + i);
      *(float4*)&x1[i] = *(const float4*)(wapp + off + i);
    }
  } else {
#pragma unroll
    for (int i = 0; i < P; i += 2) {
      *(float2*)&x0[i] = *(const float2*)(wdet + off + i);
      *(float2*)&x1[i] = *(const float2*)(wapp + off + i);
    }
  }
}

// K4: block=(b,d,kg); wave wv = full chain k=kg*4+wv through levels 3..0.
// Software-pipelined: weight staging split into issue (global->reg) and
// commit (reg->LDS, double-buffered slots); chi loads for level l-1 issued
// before conv of level l.
__global__ __launch_bounds__(256, 2) void k_lc(const float* __restrict__ wdet,
                                               const float* __restrict__ wapp,
                                               const float* __restrict__ curd,
                                               const float* __restrict__ lcw_re,
                                               float* __restrict__ osum01,
                                               float* __restrict__ osum23) {
  __shared__ float wbuf[4][2][584];  // [wave][slot] weight slabs
  __shared__ float accb[2][2112];    // two reduction slabs, +33 padded
  const int tid = threadIdx.x;
  const int lane = tid & 63;
  const int wv = tid >> 6;
  const int kg = blockIdx.x & 3;
  const int d = (blockIdx.x >> 2) & 31;
  const int b = blockIdx.x >> 7;
  const int k = kg * 4 + wv;
  const int bk = b * 16 + k;
  const int dk = d * 16 + k;
  const int seg = lane >> 3;  // same seg mapping at every level
  const size_t base = (size_t)bk * 1920;

  struct StReg { float4 a, b, c; };
  auto stage_issue = [&](int l) {
    const float4* src = (const float4*)(lcw_re + ((size_t)(l * 512) + dk) * 576);
    StReg r;
    r.a = src[lane];
    r.b = src[lane + 64];
    if (lane < 16) r.c = src[lane + 128];
    return r;
  };
  auto stage_commit = [&](const StReg& r, int slot) {
    float4* dst = (float4*)wbuf[wv][slot];
    dst[lane] = r.a;
    dst[lane + 64] = r.b;
    if (lane < 16) dst[lane + 128] = r.c;
  };

  // -------- prologue: issue L3+L2 weights, L3+L2 chi, curd ----------
  StReg r3 = stage_issue(3);
  StReg r2 = stage_issue(2);
  float c3x0[2], c3x1[2], c3[2];
  load_chi<2>(wdet, wapp, base + 1792 + lane * 2, c3x0, c3x1);
  *(float2*)&c3[0] =
      *(const float2*)(curd + (((size_t)b * 32 + d) * 16 + k) * 128 + lane * 2);
  float c2x0[4], c2x1[4];
  load_chi<4>(wdet, wapp, base + 1536 + lane * 4, c2x0, c2x1);
  stage_commit(r3, 0);

  // ---- level 3 (P=2) ----
  float cur4[4];
  conv3<2>(lane, wbuf[wv][0], seg, c3x0, c3x1);
  haar_rec_reg<2>(c3x0, c3x1, c3, cur4);

  // issue L1 ahead
  StReg r1 = stage_issue(1);
  float c1x0[8], c1x1[8];
  load_chi<8>(wdet, wapp, base + 1024 + lane * 8, c1x0, c1x1);
  stage_commit(r2, 1);

  // ---- level 2 (P=4) ----
  float cur8[8];
  conv3<4>(lane, wbuf[wv][1], seg, c2x0, c2x1);
  haar_rec_reg<4>(c2x0, c2x1, cur4, cur8);

  // issue L0 ahead
  StReg r0 = stage_issue(0);
  float c0x0[16], c0x1[16];
  load_chi<16>(wdet, wapp, base + lane * 16, c0x0, c0x1);
  stage_commit(r1, 0);

  // ---- level 1 (P=8) ----
  float cur16[16];
  conv3<8>(lane, wbuf[wv][0], seg, c1x0, c1x1);
  haar_rec_reg<8>(c1x0, c1x1, cur8, cur16);
  stage_commit(r0, 1);

  // ---- level 0 (P=16), final rec fused into the two-phase LDS reduction ----
  {
    conv3<16>(lane, wbuf[wv][1], seg, c0x0, c0x1);
    float* arow = &accb[wv & 1][lane * 33];
    if (wv >= 2) {  // waves 2,3 initialize the two slabs
#pragma unroll
      for (int i = 0; i < 16; ++i) {
        float X1 = c0x1[i] + cur16[i], X0 = c0x0[i];
        arow[2 * i] = (X1 + X0) * SQC;
        arow[2 * i + 1] = (X1 - X0) * SQC;
      }
    }
    __syncthreads();
    if (wv < 2) {  // waves 0,1 accumulate into them
#pragma unroll
      for (int i = 0; i < 16; ++i) {
        float X1 = c0x1[i] + cur16[i], X0 = c0x0[i];
        arow[2 * i] += (X1 + X0) * SQC;
        arow[2 * i + 1] += (X1 - X0) * SQC;
      }
    }
  }
  __syncthreads();
  // block reduction over the 2 slabs -> one osum partial slab row
  float* obase = (kg < 2) ? osum01 : osum23;
  float* orow = obase + ((size_t)(kg & 1) * 512 + (size_t)b * 32 + d) * 2048;
#pragma unroll
  for (int r = 0; r < 8; ++r) {
    int p = r * 256 + tid;
    int L = p >> 5, J = p & 31;
    int a = L * 33 + J;
    orow[p] = accb[0][a] + accb[1][a];
  }
}

// ------- K5: U[b,l,Dq] = sum_d (sum of 4 osum slabs) * Wrev[d,Dq] -----------
__global__ __launch_bounds__(256) void k_final(const float* __restrict__ osum01,
                                               const float* __restrict__ osum23,
                                               const float* __restrict__ Wrev,
                                               float* __restrict__ U) {
  int t = (blockIdx.x >> 2) * 256 + threadIdx.x;
  int Dq = blockIdx.x & 3;
  int b = t >> 11, l = t & 2047;
  float acc[16];
#pragma unroll
  for (int i = 0; i < 16; ++i) acc[i] = 0.f;
  for (int dd = 0; dd < 32; ++dd) {
    size_t off = ((size_t)b * 32 + dd) * 2048 + l;
    float x = osum01[off] + osum01[off + 1048576] +
              osum23[off] + osum23[off + 1048576];
    const float* wr = Wrev + dd * 64 + Dq * 16;
#pragma unroll
    for (int j = 0; j < 16; ++j) acc[j] = fmaf(x, wr[j], acc[j]);
  }
  float* o = U + (size_t)t * 64 + Dq * 16;
#pragma unroll
  for (int i = 0; i < 4; ++i)
    *(float4*)(o + 4 * i) =
        make_float4(acc[4 * i], acc[4 * i + 1], acc[4 * i + 2], acc[4 * i + 3]);
}

extern "C" void kernel_launch(void* const* d_in, const int* in_sizes, int n_in,
                              void* d_out, int out_size, void* d_ws, size_t ws_size,
                              hipStream_t stream) {
  const float* seq    = (const float*)d_in[0];
  const float* coeffs = (const float*)d_in[1];
  // d_in[2]=time, d_in[3]=time_step: arange(2048), dt==1 -> folded.
  const float* Wg   = (const float*)d_in[4];
  const float* Wh   = (const float*)d_in[5];
  const float* dW   = (const float*)d_in[6];
  const float* lcw  = (const float*)d_in[7];
  const float* lcb  = (const float*)d_in[8];
  const float* Wrev = (const float*)d_in[9];
  float* out = (float*)d_out;

  // workspace layout (float units), aliased by lifetime:
  float* w      = (float*)d_ws;
  float* v      = w + 1048576;    //   524,288  [k_zv -> k_haar]
  float* a0T    = w + 1572864;    //    32,768  [k_haar -> dense]
  unsigned short* WhT = (unsigned short*)(w + 1572864 + 16384);  // [prep -> k_zv]
  float* lcw_re = w + 1605632;    // 1,179,648  [prep -> k_lc]
  float* curd   = w + 3702784;    // 1,048,576  [dense3 -> k_lc]
  float* osum01 = w + 4751360;    // 2,097,152  [k_lc -> final]
  float* wdet   = w + 6848512;    //   491,520  [k_haar -> k_lc]
  float* wapp   = w + 7340032;    //   491,520
  float* osum23 = w + 7831552;    // 2,097,152  [k_lc -> final]  (~39.7 MB)

  k_prep_all<<<4736, 256, 0, stream>>>(Wh, WhT, lcw, lcb, lcw_re);
  k_zv<<<512, 256, 0, stream>>>(seq, Wg, coeffs, WhT, v);
  k_haar<<<256, 64, 0, stream>>>(v, wdet, wapp, a0T);
  k_dense3<<<512, 256, 0, stream>>>(dW, a0T, curd);
  k_lc<<<2048, 256, 0, stream>>>(wdet, wapp, curd, lcw_re, osum01, osum23);
  k_final<<<512, 256, 0, stream>>>(osum01, osum23, Wrev, out);
}